// Round 1
// baseline (18828.928 us; speedup 1.0000x reference)
//
#include <hip/hip_runtime.h>
#include <cfloat>
#include <cmath>

// ---- problem constants ----
constexpr int kV    = 50257;
constexpr int kD    = 768;
constexpr int NLY   = 2;
constexpr int BB    = 4;
constexpr int BEAM  = 5;
constexpr int RR    = BB * BEAM;   // 20 rows
constexpr int BUFL  = 17;          // TMAX+1
constexpr int SS    = 128;
constexpr int DFF   = 3072;
constexpr int TMAX  = 16;
constexpr int SOS   = 1;
constexpr int EOSt  = 2;
#define NEGV (-1e20f)

// ---------------- wave/block reductions ----------------
__device__ inline float wave_sum(float v) {
#pragma unroll
  for (int o = 32; o > 0; o >>= 1) v += __shfl_xor(v, o, 64);
  return v;
}
__device__ inline float wave_max(float v) {
#pragma unroll
  for (int o = 32; o > 0; o >>= 1) v = fmaxf(v, __shfl_xor(v, o, 64));
  return v;
}
// 256-thread block sum; all threads get the total. red = __shared__ float[4].
__device__ inline float block_sum256(float v, float* red) {
  v = wave_sum(v);
  __syncthreads();
  if ((threadIdx.x & 63) == 0) red[threadIdx.x >> 6] = v;
  __syncthreads();
  return red[0] + red[1] + red[2] + red[3];
}

// ---------------- init ----------------
__global__ void init_k(int* buf0, float* scores) {
  int tid = threadIdx.x;
  if (tid < RR * BUFL) buf0[tid] = 0;
  __syncthreads();
  if (tid < BB) buf0[tid * BEAM * BUFL] = SOS;   // buf[b][0][0] = SOS
  if (tid < RR) scores[tid] = (tid % BEAM == 0) ? 0.f : NEGV;
}

// ---------------- cross K/V precompute (once per call) ----------------
// grid (32, 96, NLY), 256 thr. rows = B*S = 512, cols = 2*D (K then V).
__global__ void cross_kv_k(const float* __restrict__ ctx, const float* __restrict__ w,
                           const float* __restrict__ bias, float* __restrict__ ck,
                           float* __restrict__ cv) {
  const int l   = blockIdx.z;
  const int row = blockIdx.x * 16 + (threadIdx.x >> 4);   // 0..511
  const int col = blockIdx.y * 16 + (threadIdx.x & 15);   // 0..1535
  const float4* a4 = (const float4*)(ctx + (size_t)row * kD);
  const float4* w4 = (const float4*)(w + ((size_t)l * 3 * kD + kD + col) * kD);
  float acc = 0.f;
  for (int k4 = 0; k4 < kD / 4; ++k4) {
    float4 a = a4[k4], ww = w4[k4];
    acc = fmaf(a.x, ww.x, fmaf(a.y, ww.y, fmaf(a.z, ww.z, fmaf(a.w, ww.w, acc))));
  }
  acc += bias[(size_t)l * 3 * kD + kD + col];
  const int b = row >> 7, s = row & 127;
  const int kv = col / kD, n = col - kv * kD;
  float* dst = kv ? cv : ck;
  dst[(((size_t)l * BB + b) * SS + s) * kD + n] = acc;
}

// ---------------- embedding + LN ----------------
__global__ void embed_ln_k(const float* __restrict__ emb, const float* __restrict__ pos,
                           const int* __restrict__ bufc, const float* __restrict__ g,
                           const float* __restrict__ be, float* __restrict__ x, int t) {
  const int r = blockIdx.x, tid = threadIdx.x;
  __shared__ float red[4];
  const int tok = bufc[r * BUFL + t];
  float v[3];
#pragma unroll
  for (int j = 0; j < 3; ++j) {
    int n = tid + j * 256;
    v[j] = emb[(size_t)tok * kD + n] + pos[(size_t)t * kD + n];
  }
  float mean = block_sum256(v[0] + v[1] + v[2], red) / 768.f;
  float q = 0.f;
#pragma unroll
  for (int j = 0; j < 3; ++j) { float d = v[j] - mean; q += d * d; }
  float var = block_sum256(q, red) / 768.f;
  float rstd = 1.f / sqrtf(var + 1e-5f);
#pragma unroll
  for (int j = 0; j < 3; ++j) {
    int n = tid + j * 256;
    x[(size_t)r * kD + n] = (v[j] - mean) * rstd * g[n] + be[n];
  }
}

// ---------------- split-K skinny GEMM: part[ks][r][n] = sum_{k in chunk} A[r][k]*W[n][k]
// grid (N/64, KS), 64 threads. chunk = 192 (K=768→KS=4, K=3072→KS=16).
__global__ __launch_bounds__(64) void gemm_part_k(const float* __restrict__ A,
                                                  const float* __restrict__ W,
                                                  float* __restrict__ part, int K, int N) {
  __shared__ float a_s[RR * 192];
  const int ks = blockIdx.y, tid = threadIdx.x;
  const int kbase = ks * 192;
  for (int i = tid; i < RR * 192; i += 64) {
    int r = i / 192, kk = i - r * 192;
    a_s[i] = A[(size_t)r * K + kbase + kk];
  }
  __syncthreads();
  const int col = blockIdx.x * 64 + tid;
  if (col >= N) return;
  float acc[RR];
#pragma unroll
  for (int r = 0; r < RR; ++r) acc[r] = 0.f;
  const float4* w4 = (const float4*)(W + (size_t)col * K + kbase);
  const float4* a4 = (const float4*)a_s;
  for (int k4 = 0; k4 < 48; ++k4) {
    float4 w = w4[k4];
#pragma unroll
    for (int r = 0; r < RR; ++r) {
      float4 a = a4[r * 48 + k4];
      acc[r] = fmaf(w.x, a.x, fmaf(w.y, a.y, fmaf(w.z, a.z, fmaf(w.w, a.w, acc[r]))));
    }
  }
  float* pdst = part + ((size_t)ks * RR) * N + col;
#pragma unroll
  for (int r = 0; r < RR; ++r) pdst[(size_t)r * N] = acc[r];
}

// ---------------- reduce split-K + bias (+activation) ----------------
__global__ void reduce_act_k(const float* __restrict__ part, const float* __restrict__ bias,
                             float* __restrict__ out, int N, int KS, int act) {
  const int flat = blockIdx.x * 256 + threadIdx.x;
  if (flat >= RR * N) return;
  const int r = flat / N, n = flat - r * N;
  float s = bias[n];
  for (int ks = 0; ks < KS; ++ks) s += part[((size_t)ks * RR + r) * N + n];
  if (act == 1) s = fmaxf(s, 0.f);
  else if (act == 2) s = tanhf(s);
  out[(size_t)r * N + n] = s;
}

// reduce for QKV: q -> qb, k/v -> caches at position t
__global__ void reduce_qkv_k(const float* __restrict__ part, const float* __restrict__ bias,
                             float* __restrict__ qb, float* __restrict__ kcl,
                             float* __restrict__ vcl, int t) {
  const int flat = blockIdx.x * 256 + threadIdx.x;
  if (flat >= RR * 3 * kD) return;
  const int r = flat / (3 * kD), n = flat - r * (3 * kD);
  float s = bias[n];
  for (int ks = 0; ks < 4; ++ks) s += part[((size_t)ks * RR + r) * (3 * kD) + n];
  if (n < kD)            qb[(size_t)r * kD + n] = s;
  else if (n < 2 * kD)   kcl[((size_t)r * BUFL + t) * kD + (n - kD)] = s;
  else                   vcl[((size_t)r * BUFL + t) * kD + (n - 2 * kD)] = s;
}

// ---------------- reduce split-K + bias + residual + LayerNorm (in-place on x) ----------------
__global__ void ln_reduce_k(const float* __restrict__ part, const float* __restrict__ bias,
                            float* __restrict__ x, const float* __restrict__ g,
                            const float* __restrict__ be, int KS) {
  const int r = blockIdx.x, tid = threadIdx.x;
  __shared__ float red[4];
  float v[3];
#pragma unroll
  for (int j = 0; j < 3; ++j) {
    int n = tid + j * 256;
    float s = x[(size_t)r * kD + n] + bias[n];
    for (int ks = 0; ks < KS; ++ks) s += part[((size_t)ks * RR + r) * kD + n];
    v[j] = s;
  }
  float mean = block_sum256(v[0] + v[1] + v[2], red) / 768.f;
  float q = 0.f;
#pragma unroll
  for (int j = 0; j < 3; ++j) { float d = v[j] - mean; q += d * d; }
  float var = block_sum256(q, red) / 768.f;
  float rstd = 1.f / sqrtf(var + 1e-5f);
#pragma unroll
  for (int j = 0; j < 3; ++j) {
    int n = tid + j * 256;
    x[(size_t)r * kD + n] = (v[j] - mean) * rstd * g[n] + be[n];
  }
}

// ---------------- causal self-attention for the new position (keys 0..t from cache) ----------------
// grid (RR, H), 64 threads (1 wave). Masked keys get exp()->0, matching ref's -10000 bias exactly.
__global__ __launch_bounds__(64) void self_attn_k(const float* __restrict__ qb,
                                                  const float* __restrict__ kc,
                                                  const float* __restrict__ vc,
                                                  float* __restrict__ outb, int t) {
  const int r = blockIdx.x, hh = blockIdx.y, lane = threadIdx.x;
  __shared__ float qs[64];
  __shared__ float ps[64];
  qs[lane] = qb[(size_t)r * kD + hh * 64 + lane];
  __syncthreads();
  float s = -1e30f;
  if (lane <= t) {
    const float* krow = kc + ((size_t)r * BUFL + lane) * kD + hh * 64;
    float acc = 0.f;
    for (int d = 0; d < 64; ++d) acc = fmaf(qs[d], krow[d], acc);
    s = acc * 0.125f;
  }
  float m = wave_max(s);
  float p = expf(s - m);          // lanes > t underflow to exactly 0
  float sum = wave_sum(p);
  ps[lane] = p / sum;
  __syncthreads();
  const float* vb = vc + (size_t)r * BUFL * kD + hh * 64 + lane;
  float o = 0.f;
  for (int k = 0; k <= t; ++k) o = fmaf(ps[k], vb[(size_t)k * kD], o);
  outb[(size_t)r * kD + hh * 64 + lane] = o;
}

// ---------------- cross-attention over S=128 precomputed keys ----------------
__global__ __launch_bounds__(64) void cross_attn_k(const float* __restrict__ qb,
                                                   const float* __restrict__ ck,
                                                   const float* __restrict__ cv,
                                                   const int* __restrict__ smask,
                                                   float* __restrict__ outb) {
  const int r = blockIdx.x, hh = blockIdx.y, lane = threadIdx.x;
  const int b = r / BEAM;
  __shared__ float qs[64];
  __shared__ float ps[128];
  qs[lane] = qb[(size_t)r * kD + hh * 64 + lane];
  __syncthreads();
  float s0, s1;
  {
    const float* k0 = ck + ((size_t)b * SS + lane) * kD + hh * 64;
    const float* k1 = k0 + (size_t)64 * kD;
    float a0 = 0.f, a1 = 0.f;
    for (int d = 0; d < 64; ++d) { a0 = fmaf(qs[d], k0[d], a0); a1 = fmaf(qs[d], k1[d], a1); }
    s0 = a0 * 0.125f; s1 = a1 * 0.125f;
    if (smask[b * SS + lane] == 0)      s0 = -1e9f;   // ref replaces (not adds)
    if (smask[b * SS + lane + 64] == 0) s1 = -1e9f;
  }
  float m = wave_max(fmaxf(s0, s1));
  float p0 = expf(s0 - m), p1 = expf(s1 - m);
  float sum = wave_sum(p0 + p1);
  ps[lane] = p0 / sum; ps[lane + 64] = p1 / sum;
  __syncthreads();
  const float* vb = cv + (size_t)b * SS * kD + hh * 64 + lane;
  float o = 0.f;
  for (int k = 0; k < SS; ++k) o = fmaf(ps[k], vb[(size_t)k * kD], o);
  outb[(size_t)r * kD + hh * 64 + lane] = o;
}

// ---------------- logits = h @ emb^T ; h (20x768) staged in LDS ----------------
__global__ __launch_bounds__(256) void logits_k(const float* __restrict__ h,
                                                const float* __restrict__ emb,
                                                float* __restrict__ lg) {
  __shared__ float hs[RR * kD];
  for (int i = threadIdx.x; i < RR * kD; i += 256) hs[i] = h[i];
  __syncthreads();
  const int col = blockIdx.x * 256 + threadIdx.x;
  if (col >= kV) return;
  const float4* e4 = (const float4*)(emb + (size_t)col * kD);
  const float4* h4 = (const float4*)hs;
  float acc[RR];
#pragma unroll
  for (int r = 0; r < RR; ++r) acc[r] = 0.f;
  for (int k4 = 0; k4 < kD / 4; ++k4) {
    float4 w = e4[k4];
#pragma unroll
    for (int r = 0; r < RR; ++r) {
      float4 a = h4[r * (kD / 4) + k4];
      acc[r] = fmaf(w.x, a.x, fmaf(w.y, a.y, fmaf(w.z, a.z, fmaf(w.w, a.w, acc[r]))));
    }
  }
#pragma unroll
  for (int r = 0; r < RR; ++r) lg[(size_t)r * kV + col] = acc[r];
}

// ---------------- log-sum-exp per row ----------------
__global__ void lse_k(const float* __restrict__ lg, float* __restrict__ lse) {
  const int r = blockIdx.x, tid = threadIdx.x;
  __shared__ float red[4];
  float m = -FLT_MAX;
  for (int v = tid; v < kV; v += 256) m = fmaxf(m, lg[(size_t)r * kV + v]);
  m = wave_max(m);
  if ((tid & 63) == 0) red[tid >> 6] = m;
  __syncthreads();
  m = fmaxf(fmaxf(red[0], red[1]), fmaxf(red[2], red[3]));
  __syncthreads();
  float s = 0.f;
  for (int v = tid; v < kV; v += 256) s += expf(lg[(size_t)r * kV + v] - m);
  s = wave_sum(s);
  if ((tid & 63) == 0) red[tid >> 6] = s;
  __syncthreads();
  if (tid == 0) lse[r] = m + logf(red[0] + red[1] + red[2] + red[3]);
}

// ---------------- per-batch top-5 over BEAM*V candidates ----------------
// Tie-break: higher value wins; equal values -> lower index (matches jax.lax.top_k).
__device__ inline bool cand_better(float v1, int i1, float v2, int i2) {
  return v1 > v2 || (v1 == v2 && i1 < i2);
}
__global__ __launch_bounds__(256) void topk_k(const float* __restrict__ lg,
                                              const float* __restrict__ lse,
                                              float* __restrict__ scores,
                                              const int* __restrict__ bufc, int t,
                                              int* __restrict__ prevK, int* __restrict__ tokv) {
  const int b = blockIdx.x, tid = threadIdx.x;
  __shared__ float lv[256 * 5];
  __shared__ int   li[256 * 5];
  float sc[BEAM]; int em[BEAM];
#pragma unroll
  for (int j = 0; j < BEAM; ++j) {
    sc[j] = scores[b * BEAM + j];
    em[j] = (bufc[(b * BEAM + j) * BUFL + t] == EOSt);
  }
  float tv[5]; int ti[5];
#pragma unroll
  for (int s = 0; s < 5; ++s) { tv[s] = -FLT_MAX; ti[s] = 0x7fffffff; }
  const int tot = BEAM * kV;
  for (int i = tid; i < tot; i += 256) {
    const int j = i / kV;
    const int v = i - j * kV;
    float val = em[j] ? NEGV
                      : (lg[(size_t)(b * BEAM + j) * kV + v] - lse[b * BEAM + j] + sc[j]);
    if (cand_better(val, i, tv[4], ti[4])) {
      tv[4] = val; ti[4] = i;
#pragma unroll
      for (int s = 4; s > 0; --s)
        if (cand_better(tv[s], ti[s], tv[s - 1], ti[s - 1])) {
          float fv = tv[s]; tv[s] = tv[s - 1]; tv[s - 1] = fv;
          int iv = ti[s]; ti[s] = ti[s - 1]; ti[s - 1] = iv;
        }
    }
  }
#pragma unroll
  for (int s = 0; s < 5; ++s) { lv[tid * 5 + s] = tv[s]; li[tid * 5 + s] = ti[s]; }
  __syncthreads();
  if (tid == 0) {
    float bv[5]; int bi[5];
#pragma unroll
    for (int s = 0; s < 5; ++s) { bv[s] = -FLT_MAX; bi[s] = 0x7fffffff; }
    for (int q = 0; q < 256 * 5; ++q) {
      float val = lv[q]; int idx = li[q];
      if (cand_better(val, idx, bv[4], bi[4])) {
        bv[4] = val; bi[4] = idx;
#pragma unroll
        for (int s = 4; s > 0; --s)
          if (cand_better(bv[s], bi[s], bv[s - 1], bi[s - 1])) {
            float fv = bv[s]; bv[s] = bv[s - 1]; bv[s - 1] = fv;
            int iv = bi[s]; bi[s] = bi[s - 1]; bi[s - 1] = iv;
          }
      }
    }
#pragma unroll
    for (int j = 0; j < 5; ++j) {
      scores[b * BEAM + j] = bv[j];
      int pk = bi[j] / kV;
      prevK[b * BEAM + j] = pk;
      tokv[b * BEAM + j]  = bi[j] - pk * kV;
    }
  }
}

// ---------------- beam reorder: buf ----------------
__global__ void reorder_buf_k(const int* __restrict__ bo, int* __restrict__ bn,
                              const int* __restrict__ pk, const int* __restrict__ tk, int t) {
  const int tid = threadIdx.x;
  if (tid >= RR * BUFL) return;
  const int r = tid / BUFL, p = tid - r * BUFL;
  const int src = (r / BEAM) * BEAM + pk[r];
  int val = bo[src * BUFL + p];
  if (p == t + 1) val = tk[r];
  bn[r * BUFL + p] = val;
}

// ---------------- beam reorder: KV caches (positions 0..t) ----------------
__global__ void reorder_cache_k(const float* __restrict__ kco, const float* __restrict__ vco,
                                float* __restrict__ kcn, float* __restrict__ vcn,
                                const int* __restrict__ pk) {
  const int r = blockIdx.x, p = blockIdx.y, z = blockIdx.z;
  const int l = z >> 1, which = z & 1;
  const int src = (r / BEAM) * BEAM + pk[r];
  const float* sp = (which ? vco : kco) + (((size_t)l * RR + src) * BUFL + p) * kD;
  float* dp = (which ? vcn : kcn) + (((size_t)l * RR + r) * BUFL + p) * kD;
  for (int i = threadIdx.x; i < kD; i += 256) dp[i] = sp[i];
}

// ---------------- finalize: scores + masked preds to d_out (as float) ----------------
__global__ void finalize_k(const float* __restrict__ scores, const int* __restrict__ buf,
                           float* __restrict__ out) {
  const int tid = threadIdx.x;
  if (tid < RR) {
    out[tid] = scores[tid];
    int seen = 0;
    for (int i = 0; i < TMAX; ++i) {
      int tk = buf[tid * BUFL + 1 + i];
      if (tk == EOSt) seen = 1;
      out[RR + tid * TMAX + i] = seen ? 0.f : (float)tk;
    }
  }
}

// ================= host side =================
extern "C" void kernel_launch(void* const* d_in, const int* in_sizes, int n_in,
                              void* d_out, int out_size, void* d_ws, size_t ws_size,
                              hipStream_t stream) {
  const float* emb        = (const float*)d_in[0];
  const float* pos        = (const float*)d_in[1];
  const float* ln_emb_g   = (const float*)d_in[2];
  const float* ln_emb_b   = (const float*)d_in[3];
  const float* self_in_w  = (const float*)d_in[4];
  const float* self_in_b  = (const float*)d_in[5];
  const float* self_out_w = (const float*)d_in[6];
  const float* self_out_b = (const float*)d_in[7];
  const float* cross_in_w = (const float*)d_in[8];
  const float* cross_in_b = (const float*)d_in[9];
  const float* cross_out_w= (const float*)d_in[10];
  const float* cross_out_b= (const float*)d_in[11];
  const float* ff1_w      = (const float*)d_in[12];
  const float* ff1_b      = (const float*)d_in[13];
  const float* ff2_w      = (const float*)d_in[14];
  const float* ff2_b      = (const float*)d_in[15];
  const float* ln1_g      = (const float*)d_in[16];
  const float* ln1_b      = (const float*)d_in[17];
  const float* ln2_g      = (const float*)d_in[18];
  const float* ln2_b      = (const float*)d_in[19];
  const float* ln3_g      = (const float*)d_in[20];
  const float* ln3_b      = (const float*)d_in[21];
  const float* dense_w    = (const float*)d_in[22];
  const float* dense_b    = (const float*)d_in[23];
  const float* context    = (const float*)d_in[24];
  const int*   source_mask= (const int*)d_in[25];

  float* wsf = (float*)d_ws;
  size_t o = 0;
  float* x     = wsf + o; o += RR * kD;
  float* qb    = wsf + o; o += RR * kD;
  float* attn  = wsf + o; o += RR * kD;
  float* ffb   = wsf + o; o += RR * DFF;
  float* hbuf  = wsf + o; o += RR * kD;
  float* part  = wsf + o; o += 16 * RR * kD;          // max split-K partials (245760)
  float* lg    = wsf + o; o += (size_t)RR * kV;
  float* lseb  = wsf + o; o += 32;
  float* scores= wsf + o; o += 32;
  float* cK    = wsf + o; o += (size_t)NLY * BB * SS * kD;
  float* cV    = wsf + o; o += (size_t)NLY * BB * SS * kD;
  const size_t cachesz = (size_t)NLY * RR * BUFL * kD;
  float* kc[2]; float* vc[2];
  kc[0] = wsf + o; o += cachesz;
  vc[0] = wsf + o; o += cachesz;
  kc[1] = wsf + o; o += cachesz;
  vc[1] = wsf + o; o += cachesz;
  int* ip = (int*)(wsf + o);
  int* bufs[2];
  bufs[0] = ip;        ip += RR * BUFL + 4;
  bufs[1] = ip;        ip += RR * BUFL + 4;
  int* prevKp = ip;    ip += 32;
  int* tokp   = ip;

  init_k<<<1, 512, 0, stream>>>(bufs[0], scores);
  cross_kv_k<<<dim3(32, 96, NLY), 256, 0, stream>>>(context, cross_in_w, cross_in_b, cK, cV);

  int cur = 0;
  for (int t = 0; t < TMAX; ++t) {
    const int* bc = bufs[cur];
    int* bn = bufs[1 - cur];
    float *kcc = kc[cur], *vcc = vc[cur], *kcn = kc[1 - cur], *vcn = vc[1 - cur];

    embed_ln_k<<<RR, 256, 0, stream>>>(emb, pos, bc, ln_emb_g, ln_emb_b, x, t);

    for (int l = 0; l < NLY; ++l) {
      float* kcl = kcc + (size_t)l * RR * BUFL * kD;
      float* vcl = vcc + (size_t)l * RR * BUFL * kD;
      // self-attention
      gemm_part_k<<<dim3(36, 4), 64, 0, stream>>>(x, self_in_w + (size_t)l * 3 * kD * kD, part, kD, 3 * kD);
      reduce_qkv_k<<<180, 256, 0, stream>>>(part, self_in_b + l * 3 * kD, qb, kcl, vcl, t);
      self_attn_k<<<dim3(RR, 12), 64, 0, stream>>>(qb, kcl, vcl, attn, t);
      gemm_part_k<<<dim3(12, 4), 64, 0, stream>>>(attn, self_out_w + (size_t)l * kD * kD, part, kD, kD);
      ln_reduce_k<<<RR, 256, 0, stream>>>(part, self_out_b + l * kD, x, ln1_g + l * kD, ln1_b + l * kD, 4);
      // cross-attention
      gemm_part_k<<<dim3(12, 4), 64, 0, stream>>>(x, cross_in_w + (size_t)l * 3 * kD * kD, part, kD, kD);
      reduce_act_k<<<60, 256, 0, stream>>>(part, cross_in_b + l * 3 * kD, qb, kD, 4, 0);
      cross_attn_k<<<dim3(RR, 12), 64, 0, stream>>>(qb, cK + (size_t)l * BB * SS * kD,
                                                    cV + (size_t)l * BB * SS * kD, source_mask, attn);
      gemm_part_k<<<dim3(12, 4), 64, 0, stream>>>(attn, cross_out_w + (size_t)l * kD * kD, part, kD, kD);
      ln_reduce_k<<<RR, 256, 0, stream>>>(part, cross_out_b + l * kD, x, ln2_g + l * kD, ln2_b + l * kD, 4);
      // feed-forward
      gemm_part_k<<<dim3(48, 4), 64, 0, stream>>>(x, ff1_w + (size_t)l * DFF * kD, part, kD, DFF);
      reduce_act_k<<<240, 256, 0, stream>>>(part, ff1_b + l * DFF, ffb, DFF, 4, 1);
      gemm_part_k<<<dim3(12, 16), 64, 0, stream>>>(ffb, ff2_w + (size_t)l * kD * DFF, part, DFF, kD);
      ln_reduce_k<<<RR, 256, 0, stream>>>(part, ff2_b + l * kD, x, ln3_g + l * kD, ln3_b + l * kD, 16);
    }

    // output head
    gemm_part_k<<<dim3(12, 4), 64, 0, stream>>>(x, dense_w, part, kD, kD);
    reduce_act_k<<<60, 256, 0, stream>>>(part, dense_b, hbuf, kD, 4, 2);
    logits_k<<<(kV + 255) / 256, 256, 0, stream>>>(hbuf, emb, lg);
    lse_k<<<RR, 256, 0, stream>>>(lg, lseb);
    topk_k<<<BB, 256, 0, stream>>>(lg, lseb, scores, bc, t, prevKp, tokp);

    // beam reorder
    reorder_buf_k<<<1, 512, 0, stream>>>(bc, bn, prevKp, tokp, t);
    if (t + 1 < TMAX)
      reorder_cache_k<<<dim3(RR, t + 1, NLY * 2), 256, 0, stream>>>(kcc, vcc, kcn, vcn, prevKp);
    cur ^= 1;
  }

  finalize_k<<<1, 64, 0, stream>>>(scores, bufs[cur], (float*)d_out);
}

// Round 2
// 11197.438 us; speedup vs baseline: 1.6815x; 1.6815x over previous
//
#include <hip/hip_runtime.h>
#include <cfloat>
#include <cmath>

// ---- problem constants ----
constexpr int kV   = 50257;
constexpr int kVP  = 50432;   // padded vocab stride for embT (= 197*256)
constexpr int kD   = 768;
constexpr int NLY  = 2;
constexpr int BB   = 4;
constexpr int BEAM = 5;
constexpr int RR   = BB * BEAM;   // 20 rows
constexpr int BUFL = 17;
constexpr int SS   = 128;
constexpr int DFF  = 3072;
constexpr int TMAX = 16;
constexpr int SOS  = 1;
constexpr int EOSt = 2;
constexpr int LB   = (kV + 255) / 256;  // 197 logits blocks
#define NEGV (-1e20f)

// ---------------- wave helpers ----------------
__device__ inline float wave_sum(float v) {
#pragma unroll
  for (int o = 32; o > 0; o >>= 1) v += __shfl_xor(v, o, 64);
  return v;
}
__device__ inline float wave_max(float v) {
#pragma unroll
  for (int o = 32; o > 0; o >>= 1) v = fmaxf(v, __shfl_xor(v, o, 64));
  return v;
}
__device__ inline bool better(float v1, int i1, float v2, int i2) {
  return v1 > v2 || (v1 == v2 && i1 < i2);
}
// sorted-desc 5-list insert
__device__ inline void insert5(float* tv, int* ti, float v, int i) {
  if (better(v, i, tv[4], ti[4])) {
    tv[4] = v; ti[4] = i;
#pragma unroll
    for (int s = 4; s > 0; --s)
      if (better(tv[s], ti[s], tv[s - 1], ti[s - 1])) {
        float fv = tv[s]; tv[s] = tv[s - 1]; tv[s - 1] = fv;
        int iv = ti[s]; ti[s] = ti[s - 1]; ti[s - 1] = iv;
      }
  }
}
__device__ inline float sel5f(const float* a, int i) {
  float r = a[0];
  r = (i == 1) ? a[1] : r; r = (i == 2) ? a[2] : r;
  r = (i == 3) ? a[3] : r; r = (i == 4) ? a[4] : r;
  return r;
}
__device__ inline int sel5i(const int* a, int i) {
  int r = a[0];
  r = (i == 1) ? a[1] : r; r = (i == 2) ? a[2] : r;
  r = (i == 3) ? a[3] : r; r = (i == 4) ? a[4] : r;
  return r;
}
// merge two desc-sorted 5-lists -> top5 into (av, ai)
__device__ inline void merge5(float* av, int* ai, const float* bv, const int* bi) {
  float cv[5]; int ci[5];
  int ia = 0, ib = 0;
#pragma unroll
  for (int s = 0; s < 5; ++s) {
    float va = sel5f(av, ia); int xa = sel5i(ai, ia);
    float vb = sel5f(bv, ib); int xb = sel5i(bi, ib);
    bool ta = better(va, xa, vb, xb);
    cv[s] = ta ? va : vb; ci[s] = ta ? xa : xb;
    ia += ta ? 1 : 0; ib += ta ? 0 : 1;
  }
#pragma unroll
  for (int s = 0; s < 5; ++s) { av[s] = cv[s]; ai[s] = ci[s]; }
}

// ---------------- init ----------------
__global__ void init_k(int* buf0, float* scores) {
  int tid = threadIdx.x;
  if (tid < RR * BUFL) buf0[tid] = 0;
  __syncthreads();
  if (tid < BB) buf0[tid * BEAM * BUFL] = SOS;
  if (tid < RR) scores[tid] = (tid % BEAM == 0) ? 0.f : NEGV;
}

// ---------------- transpose: dst[c*ds + r] = src[r*C + c] ----------------
__global__ void transpose_k(const float* __restrict__ src, float* __restrict__ dst,
                            int R, int C, int ds) {
  __shared__ float tile[32][33];
  const int c0 = blockIdx.x * 32, r0 = blockIdx.y * 32;
  const int lx = threadIdx.x & 31, ly = threadIdx.x >> 5;  // 32 x 8
#pragma unroll
  for (int j = 0; j < 4; ++j) {
    int r = r0 + ly + j * 8;
    if (r < R && c0 + lx < C) tile[ly + j * 8][lx] = src[(size_t)r * C + c0 + lx];
  }
  __syncthreads();
#pragma unroll
  for (int j = 0; j < 4; ++j) {
    int c = c0 + ly + j * 8;
    if (c < C && r0 + lx < R) dst[(size_t)c * ds + r0 + lx] = tile[lx][ly + j * 8];
  }
}

// ---------------- cross K/V precompute ----------------
// grid (24, 32, 2), 256 thr. 16 ctx rows per block, 64 of 1536 K/V cols, 4-wave K-split.
template<bool WT>
__global__ __launch_bounds__(256) void crosskv_k(
    const float* __restrict__ ctx, const float* __restrict__ Wm0,
    const float* __restrict__ bias0, float* __restrict__ ck, float* __restrict__ cv) {
  const int l = blockIdx.z;
  const float* Wm = Wm0 + (size_t)l * 2304 * 768;   // same element count either layout
  const float* bias = bias0 + l * 2304;
  __shared__ float a_s[16 * 768];
  __shared__ float ps[4 * 64 * 17];
  const int tid = threadIdx.x;
  const int row0 = blockIdx.y * 16;
  for (int i = tid * 4; i < 16 * 768; i += 1024) {
    int rr = i / 768, k = i - rr * 768;
    *(float4*)&a_s[i] = *(const float4*)&ctx[(size_t)(row0 + rr) * 768 + k];
  }
  __syncthreads();
  const int w = tid >> 6, lane = tid & 63;
  const int colg = 768 + blockIdx.x * 64 + lane;
  const int kb = w * 192;
  float acc[16];
#pragma unroll
  for (int r = 0; r < 16; ++r) acc[r] = 0.f;
  for (int k4 = 0; k4 < 48; ++k4) {
    const int k = kb + k4 * 4;
    float w0, w1, w2, w3;
    if (WT) {
      w0 = Wm[(size_t)(k + 0) * 2304 + colg]; w1 = Wm[(size_t)(k + 1) * 2304 + colg];
      w2 = Wm[(size_t)(k + 2) * 2304 + colg]; w3 = Wm[(size_t)(k + 3) * 2304 + colg];
    } else {
      float4 wv = *(const float4*)&Wm[(size_t)colg * 768 + k];
      w0 = wv.x; w1 = wv.y; w2 = wv.z; w3 = wv.w;
    }
#pragma unroll
    for (int r = 0; r < 16; ++r) {
      float4 a = *(const float4*)&a_s[r * 768 + k];
      acc[r] = fmaf(a.x, w0, fmaf(a.y, w1, fmaf(a.z, w2, fmaf(a.w, w3, acc[r]))));
    }
  }
#pragma unroll
  for (int r = 0; r < 16; ++r) ps[(w * 64 + lane) * 17 + r] = acc[r];
  __syncthreads();
  for (int o = tid; o < 1024; o += 256) {
    int rr = o >> 6, cl = o & 63;
    int cg = 768 + blockIdx.x * 64 + cl;
    float v = bias[cg];
#pragma unroll
    for (int ww = 0; ww < 4; ++ww) v += ps[(ww * 64 + cl) * 17 + rr];
    int gr = row0 + rr;
    int b = gr >> 7, s = gr & 127;
    int c = cg - 768, kv = c / 768, n = c - kv * 768;
    float* dst = kv ? cv : ck;
    dst[((size_t)(l * 4 + b) * 128 + s) * 768 + n] = v;
  }
}

// ---------------- fused skinny GEMM (M=20, K=768), 4-wave in-block K-split ----------------
// pre: 0 = stage xsrc raw; 1 = embed+pos+LN; 2 = LN(xsrc + tmp_in)
// outmode: 0 plain, 1 relu, 2 tanh, 3 qkv-route (qb / kcl / vcl @ pos t)
template<bool WT>
__global__ __launch_bounds__(256) void gemm20_k(
    const float* __restrict__ Wm, int wstride, const float* __restrict__ bias, int N,
    int pre, const float* __restrict__ xsrc, const float* __restrict__ tmp_in,
    const float* __restrict__ lng, const float* __restrict__ lnb, float* __restrict__ xout,
    int outmode, float* __restrict__ out0,
    float* __restrict__ kcl, float* __restrict__ vcl, int t,
    const float* __restrict__ embp, const float* __restrict__ posw, const int* __restrict__ bufn,
    int reorder_t, const float* __restrict__ kco, const float* __restrict__ vco,
    float* __restrict__ kcn, float* __restrict__ vcn, const int* __restrict__ prevK) {
  __shared__ float a_s[RR * 768];
  __shared__ float ps[4 * 64 * 21];
  __shared__ float mS[RR], rS[RR];
  __shared__ int tokS[RR];
  const int tid = threadIdx.x;

  // side job: KV-cache reorder of positions 0..reorder_t-1 (old -> new by prevK)
  if (reorder_t > 0) {
    const int per = 768 * reorder_t;
    const int tot = 2 * RR * per;
    for (int i = blockIdx.x * 256 + tid; i < tot; i += gridDim.x * 256) {
      int half = i / (RR * per);
      int rem = i - half * RR * per;
      int r = rem / per;
      int rem2 = rem - r * per;
      int p = rem2 / 768;
      int d = rem2 - p * 768;
      int src = (r / BEAM) * BEAM + prevK[r];
      if (half == 0) kcn[(r * BUFL + p) * 768 + d] = kco[(src * BUFL + p) * 768 + d];
      else           vcn[(r * BUFL + p) * 768 + d] = vco[(src * BUFL + p) * 768 + d];
    }
  }
  if (pre == 1 && tid < RR) tokS[tid] = bufn[tid * BUFL + t];
  __syncthreads();
  // ---- stage A (20x768) ----
  for (int i = tid * 4; i < RR * 768; i += 1024) {
    int r = i / 768, k = i - r * 768;
    float4 v;
    if (pre == 0) v = *(const float4*)&xsrc[i];
    else if (pre == 1) {
      float4 e = *(const float4*)&embp[(size_t)tokS[r] * 768 + k];
      float4 p = *(const float4*)&posw[(size_t)t * 768 + k];
      v = make_float4(e.x + p.x, e.y + p.y, e.z + p.z, e.w + p.w);
    } else {
      float4 a = *(const float4*)&xsrc[i];
      float4 b = *(const float4*)&tmp_in[i];
      v = make_float4(a.x + b.x, a.y + b.y, a.z + b.z, a.w + b.w);
    }
    *(float4*)&a_s[i] = v;
  }
  __syncthreads();
  if (pre != 0) {
    // in-block LayerNorm (redundant across blocks; deterministic)
    const int w0 = tid >> 6, ln = tid & 63;
    for (int r = w0 * 5; r < w0 * 5 + 5; ++r) {
      float s = 0.f, q = 0.f;
      for (int k = ln; k < 768; k += 64) { float v = a_s[r * 768 + k]; s += v; q += v * v; }
      s = wave_sum(s); q = wave_sum(q);
      if (ln == 0) {
        float m = s / 768.f;
        float var = q / 768.f - m * m;
        mS[r] = m; rS[r] = 1.f / sqrtf(var + 1e-5f);
      }
    }
    __syncthreads();
    for (int i = tid * 4; i < RR * 768; i += 1024) {
      int r = i / 768, k = i - r * 768;
      float4 v = *(const float4*)&a_s[i];
      float4 g = *(const float4*)&lng[k];
      float4 b = *(const float4*)&lnb[k];
      float m = mS[r], rs = rS[r];
      v = make_float4((v.x - m) * rs * g.x + b.x, (v.y - m) * rs * g.y + b.y,
                      (v.z - m) * rs * g.z + b.z, (v.w - m) * rs * g.w + b.w);
      *(float4*)&a_s[i] = v;
    }
    __syncthreads();
    if (xout != nullptr && blockIdx.x == 0) {
      for (int i = tid * 4; i < RR * 768; i += 1024)
        *(float4*)&xout[i] = *(const float4*)&a_s[i];
    }
  }
  // ---- compute: wave w owns K-chunk [w*192, w*192+192), lane owns column ----
  const int w = tid >> 6, lane = tid & 63;
  const int colg = blockIdx.x * 64 + lane;
  const int kb = w * 192;
  float acc[RR];
#pragma unroll
  for (int r = 0; r < RR; ++r) acc[r] = 0.f;
  for (int k4 = 0; k4 < 48; ++k4) {
    const int k = kb + k4 * 4;
    float w0, w1, w2, w3;
    if (WT) {
      w0 = Wm[(size_t)(k + 0) * wstride + colg]; w1 = Wm[(size_t)(k + 1) * wstride + colg];
      w2 = Wm[(size_t)(k + 2) * wstride + colg]; w3 = Wm[(size_t)(k + 3) * wstride + colg];
    } else {
      float4 wv = *(const float4*)&Wm[(size_t)colg * 768 + k];
      w0 = wv.x; w1 = wv.y; w2 = wv.z; w3 = wv.w;
    }
#pragma unroll
    for (int r = 0; r < RR; ++r) {
      float4 a = *(const float4*)&a_s[r * 768 + k];
      acc[r] = fmaf(a.x, w0, fmaf(a.y, w1, fmaf(a.z, w2, fmaf(a.w, w3, acc[r]))));
    }
  }
#pragma unroll
  for (int r = 0; r < RR; ++r) ps[(w * 64 + lane) * 21 + r] = acc[r];
  __syncthreads();
  for (int o = tid; o < RR * 64; o += 256) {
    int r = o >> 6, cl = o & 63;
    int cg = blockIdx.x * 64 + cl;
    float v = bias[cg];
#pragma unroll
    for (int ww = 0; ww < 4; ++ww) v += ps[(ww * 64 + cl) * 21 + r];
    if (outmode == 1) v = fmaxf(v, 0.f);
    else if (outmode == 2) v = tanhf(v);
    if (outmode == 3) {
      if (cg < 768) out0[r * 768 + cg];
      if (cg < 768) out0[r * 768 + cg] = v;
      else if (cg < 1536) kcl[(r * BUFL + t) * 768 + (cg - 768)] = v;
      else vcl[(r * BUFL + t) * 768 + (cg - 1536)] = v;
    } else {
      out0[(size_t)r * N + cg] = v;
    }
  }
}

// ---------------- ff2: M=20, K=3072, N=768; 1024 thr, 64-way (wave x lane-quarter) K-split ----------------
template<bool WT>
__global__ __launch_bounds__(1024) void ff2_k(
    const float* __restrict__ Wm, const float* __restrict__ bias,
    const float* __restrict__ A, float* __restrict__ out0) {
  __shared__ float ps[64 * 16 * 21];
  const int tid = threadIdx.x;
  const int w = tid >> 6, lane = tid & 63;
  const int cl = lane & 15, ksub = lane >> 4;
  const int colg = blockIdx.x * 16 + cl;     // grid 48
  const int kb = w * 192 + ksub * 48;
  float acc[RR];
#pragma unroll
  for (int r = 0; r < RR; ++r) acc[r] = 0.f;
  for (int k4 = 0; k4 < 12; ++k4) {
    const int k = kb + k4 * 4;
    float w0, w1, w2, w3;
    if (WT) {
      w0 = Wm[(size_t)(k + 0) * 768 + colg]; w1 = Wm[(size_t)(k + 1) * 768 + colg];
      w2 = Wm[(size_t)(k + 2) * 768 + colg]; w3 = Wm[(size_t)(k + 3) * 768 + colg];
    } else {
      float4 wv = *(const float4*)&Wm[(size_t)colg * 3072 + k];
      w0 = wv.x; w1 = wv.y; w2 = wv.z; w3 = wv.w;
    }
#pragma unroll
    for (int r = 0; r < RR; ++r) {
      float4 a = *(const float4*)&A[r * 3072 + k];
      acc[r] = fmaf(a.x, w0, fmaf(a.y, w1, fmaf(a.z, w2, fmaf(a.w, w3, acc[r]))));
    }
  }
  const int seg = w * 4 + ksub;
#pragma unroll
  for (int r = 0; r < RR; ++r) ps[(seg * 16 + cl) * 21 + r] = acc[r];
  __syncthreads();
  if (tid < RR * 16) {
    int r = tid >> 4, c2 = tid & 15;
    float v = bias[blockIdx.x * 16 + c2];
    for (int s2 = 0; s2 < 64; ++s2) v += ps[(s2 * 16 + c2) * 21 + r];
    out0[r * 768 + blockIdx.x * 16 + c2] = v;
  }
}

// ---------------- self-attention (new position, keys 0..t) ----------------
__global__ __launch_bounds__(64) void self_attn_k(
    const float* __restrict__ qb, const float* __restrict__ kcn,
    const float* __restrict__ vcn, float* __restrict__ outb, int t) {
  const int r = blockIdx.x, hh = blockIdx.y, lane = threadIdx.x;
  __shared__ float qs[64];
  __shared__ float ks[16 * 65];
  __shared__ float pp[16];
  qs[lane] = qb[r * 768 + hh * 64 + lane];
  for (int p = 0; p <= t; ++p)
    ks[p * 65 + lane] = kcn[(r * BUFL + p) * 768 + hh * 64 + lane];
  __syncthreads();
  float s = -1e30f;
  if (lane <= t) {
    float a = 0.f;
#pragma unroll
    for (int d = 0; d < 64; ++d) a = fmaf(qs[d], ks[lane * 65 + d], a);
    s = a * 0.125f;
  }
  float m = wave_max(s);
  float p = expf(s - m);           // lanes > t underflow to exact 0
  float sum = wave_sum(p);
  if (lane <= t) pp[lane] = p / sum;
  __syncthreads();
  const float* vb = vcn + r * BUFL * 768 + hh * 64 + lane;
  float o = 0.f;
  for (int k = 0; k <= t; ++k) o = fmaf(pp[k], vb[k * 768], o);
  outb[r * 768 + hh * 64 + lane] = o;
}

// ---------------- cross-attention (128 precomputed keys) ----------------
__global__ __launch_bounds__(64) void cross_attn_k(
    const float* __restrict__ qb, const float* __restrict__ ck,
    const float* __restrict__ cv, const int* __restrict__ smask,
    float* __restrict__ outb) {
  const int r = blockIdx.x, hh = blockIdx.y, lane = threadIdx.x;
  const int b = r / BEAM;
  __shared__ float qs[64];
  __shared__ float ks[128 * 65];
  __shared__ float pp[128];
  qs[lane] = qb[r * 768 + hh * 64 + lane];
  for (int p = 0; p < 128; ++p)
    ks[p * 65 + lane] = ck[((size_t)b * 128 + p) * 768 + hh * 64 + lane];
  __syncthreads();
  float a0 = 0.f, a1 = 0.f;
#pragma unroll
  for (int d = 0; d < 64; ++d) {
    a0 = fmaf(qs[d], ks[lane * 65 + d], a0);
    a1 = fmaf(qs[d], ks[(lane + 64) * 65 + d], a1);
  }
  float s0 = a0 * 0.125f, s1 = a1 * 0.125f;
  if (smask[b * 128 + lane] == 0)      s0 = -1e9f;
  if (smask[b * 128 + lane + 64] == 0) s1 = -1e9f;
  float m = wave_max(fmaxf(s0, s1));
  float p0 = expf(s0 - m), p1 = expf(s1 - m);
  float sum = wave_sum(p0 + p1);
  pp[lane] = p0 / sum; pp[lane + 64] = p1 / sum;
  __syncthreads();
  const float* vb = cv + (size_t)b * 128 * 768 + hh * 64 + lane;
  float o0 = 0.f, o1 = 0.f, o2 = 0.f, o3 = 0.f;
  for (int k = 0; k < 128; k += 4) {
    o0 = fmaf(pp[k + 0], vb[(k + 0) * 768], o0);
    o1 = fmaf(pp[k + 1], vb[(k + 1) * 768], o1);
    o2 = fmaf(pp[k + 2], vb[(k + 2) * 768], o2);
    o3 = fmaf(pp[k + 3], vb[(k + 3) * 768], o3);
  }
  outb[r * 768 + hh * 64 + lane] = (o0 + o1) + (o2 + o3);
}

// ---------------- logits + per-block online-softmax partials + per-(block,row) top-5 ----------------
template<bool ET>
__global__ __launch_bounds__(256) void logits_k(
    const float* __restrict__ hbuf, const float* __restrict__ embM,
    float* __restrict__ candV, int* __restrict__ candI,
    float* __restrict__ mrow, float* __restrict__ srow) {
  __shared__ float hs[RR * 768];
  __shared__ float vv[4 * 256];
  const int tid = threadIdx.x, blk = blockIdx.x;
  for (int i = tid * 4; i < RR * 768; i += 1024)
    *(float4*)&hs[i] = *(const float4*)&hbuf[i];
  __syncthreads();
  const int col = blk * 256 + tid;
  const bool valid = col < kV;
  const int colc = valid ? col : (kV - 1);
  float acc[RR];
#pragma unroll
  for (int r = 0; r < RR; ++r) acc[r] = 0.f;
  for (int k = 0; k < 768; k += 4) {
    float w0, w1, w2, w3;
    if (ET) {
      w0 = embM[(size_t)(k + 0) * kVP + col]; w1 = embM[(size_t)(k + 1) * kVP + col];
      w2 = embM[(size_t)(k + 2) * kVP + col]; w3 = embM[(size_t)(k + 3) * kVP + col];
    } else {
      float4 wv = *(const float4*)&embM[(size_t)colc * 768 + k];
      w0 = wv.x; w1 = wv.y; w2 = wv.z; w3 = wv.w;
    }
#pragma unroll
    for (int r = 0; r < RR; ++r) {
      float4 a = *(const float4*)&hs[r * 768 + k];
      acc[r] = fmaf(a.x, w0, fmaf(a.y, w1, fmaf(a.z, w2, fmaf(a.w, w3, acc[r]))));
    }
  }
  const int w = tid >> 6, lane = tid & 63;
  for (int g = 0; g < 5; ++g) {      // rows 4g..4g+3; wave w handles row 4g+w
#pragma unroll
    for (int j = 0; j < 4; ++j) vv[j * 256 + tid] = valid ? acc[g * 4 + j] : -FLT_MAX;
    __syncthreads();
    const int r = g * 4 + w;
    float v[4]; int gc[4]; bool used[4];
#pragma unroll
    for (int j = 0; j < 4; ++j) {
      v[j] = vv[w * 256 + lane * 4 + j];
      gc[j] = blk * 256 + lane * 4 + j;
      used[j] = false;
    }
    float tv[5]; int tg[5];
#pragma unroll
    for (int round = 0; round < 5; ++round) {
      float bv = -FLT_MAX; int bidx = 0x7fffffff; int bj = -1;
#pragma unroll
      for (int j = 0; j < 4; ++j) {
        bool c = (!used[j]) && better(v[j], gc[j], bv, bidx);
        bv = c ? v[j] : bv; bidx = c ? gc[j] : bidx; bj = c ? j : bj;
      }
      float wv2 = bv; int wi = bidx;
      for (int d = 1; d < 64; d <<= 1) {
        float ov = __shfl_xor(wv2, d, 64); int oi = __shfl_xor(wi, d, 64);
        if (better(ov, oi, wv2, wi)) { wv2 = ov; wi = oi; }
      }
      tv[round] = wv2; tg[round] = wi;
      if (bj >= 0 && bidx == wi) used[bj] = true;
    }
    float m = tv[0];
    float s = 0.f;
#pragma unroll
    for (int j = 0; j < 4; ++j) s += expf(v[j] - m);   // -FLT_MAX -> 0
    s = wave_sum(s);
    if (lane == 0) {
      mrow[r * LB + blk] = m;
      srow[r * LB + blk] = s;
#pragma unroll
      for (int q = 0; q < 5; ++q) {
        candV[(r * LB + blk) * 5 + q] = tv[q];
        candI[(r * LB + blk) * 5 + q] = tg[q];
      }
    }
    __syncthreads();
  }
}

// ---------------- per-batch top-5 over candidates + lse-reduce + buf reorder ----------------
__global__ __launch_bounds__(256) void topk_k(
    const float* __restrict__ candV, const int* __restrict__ candI,
    const float* __restrict__ mrow, const float* __restrict__ srow,
    float* __restrict__ scores, const int* __restrict__ bufc, int* __restrict__ bufn,
    int t, int* __restrict__ prevK, int* __restrict__ tokv) {
  const int b = blockIdx.x, tid = threadIdx.x;
  const int w = tid >> 6, lane = tid & 63;
  __shared__ float lseS[5], scS[5];
  __shared__ int emS[5];
  __shared__ float wv5[4][5]; __shared__ int wi5[4][5];
  __shared__ int fpk[5], ftok[5];
  // (a) lse per row (merge 197 online-softmax partials), scores, EOS flags
  for (int j = w; j < 5; j += 4) {
    const int gr = b * 5 + j;
    float M = -FLT_MAX, S = 0.f;
    for (int e = lane; e < LB; e += 64) {
      float m2 = mrow[gr * LB + e], s2 = srow[gr * LB + e];
      if (m2 > M) { S = S * expf(M - m2) + s2; M = m2; }
      else        { S += s2 * expf(m2 - M); }
    }
    for (int d = 1; d < 64; d <<= 1) {
      float Mo = __shfl_xor(M, d, 64), So = __shfl_xor(S, d, 64);
      float Mn = fmaxf(M, Mo);
      S = S * expf(M - Mn) + So * expf(Mo - Mn);
      M = Mn;
    }
    if (lane == 0) {
      lseS[j] = M + logf(S);
      scS[j] = scores[gr];
      emS[j] = (bufc[gr * BUFL + t] == EOSt);
    }
  }
  __syncthreads();
  // (b) per-thread top-5 over 5*197*5 = 4925 candidates
  float tv[5]; int ti[5];
#pragma unroll
  for (int s = 0; s < 5; ++s) { tv[s] = -FLT_MAX; ti[s] = 0x7fffffff; }
  for (int i = tid; i < 5 * LB * 5; i += 256) {
    int j = i / (LB * 5);
    int e = i - j * LB * 5;
    int blk = e / 5, rk = e - blk * 5;
    int gr = b * 5 + j;
    float cvv = candV[(gr * LB + blk) * 5 + rk];
    int col = candI[(gr * LB + blk) * 5 + rk];
    float val = emS[j] ? NEGV : (cvv - lseS[j] + scS[j]);
    insert5(tv, ti, val, j * kV + col);
  }
  // wave butterfly merge of sorted-5 lists
  for (int d = 1; d < 64; d <<= 1) {
    float ov[5]; int oi[5];
#pragma unroll
    for (int s = 0; s < 5; ++s) { ov[s] = __shfl_xor(tv[s], d, 64); oi[s] = __shfl_xor(ti[s], d, 64); }
    merge5(tv, ti, ov, oi);
  }
  if (lane == 0) {
#pragma unroll
    for (int s = 0; s < 5; ++s) { wv5[w][s] = tv[s]; wi5[w][s] = ti[s]; }
  }
  __syncthreads();
  if (tid == 0) {
    float av[5]; int ai[5];
#pragma unroll
    for (int s = 0; s < 5; ++s) { av[s] = wv5[0][s]; ai[s] = wi5[0][s]; }
    for (int ww = 1; ww < 4; ++ww) {
      float bv[5]; int bi[5];
#pragma unroll
      for (int s = 0; s < 5; ++s) { bv[s] = wv5[ww][s]; bi[s] = wi5[ww][s]; }
      merge5(av, ai, bv, bi);
    }
#pragma unroll
    for (int s = 0; s < 5; ++s) {
      int pk = ai[s] / kV;
      int tk = ai[s] - pk * kV;
      scores[b * 5 + s] = av[s];
      prevK[b * 5 + s] = pk; tokv[b * 5 + s] = tk;
      fpk[s] = pk; ftok[s] = tk;
    }
  }
  __syncthreads();
  // (c) write reordered token buffer rows for this batch
  for (int i = tid; i < 5 * BUFL; i += 256) {
    int j = i / BUFL, p = i - j * BUFL;
    int src = b * 5 + fpk[j];
    int val = (p == t + 1) ? ftok[j] : bufc[src * BUFL + p];
    bufn[(b * 5 + j) * BUFL + p] = val;
  }
}

// ---------------- finalize ----------------
__global__ void finalize_k(const float* __restrict__ scores, const int* __restrict__ buf,
                           float* __restrict__ out) {
  const int tid = threadIdx.x;
  if (tid < RR) {
    out[tid] = scores[tid];
    int seen = 0;
    for (int i = 0; i < TMAX; ++i) {
      int tk = buf[tid * BUFL + 1 + i];
      if (tk == EOSt) seen = 1;
      out[RR + tid * TMAX + i] = seen ? 0.f : (float)tk;
    }
  }
}

// ================= host side =================
extern "C" void kernel_launch(void* const* d_in, const int* in_sizes, int n_in,
                              void* d_out, int out_size, void* d_ws, size_t ws_size,
                              hipStream_t stream) {
  const float* emb        = (const float*)d_in[0];
  const float* pos        = (const float*)d_in[1];
  const float* ln_emb_g   = (const float*)d_in[2];
  const float* ln_emb_b   = (const float*)d_in[3];
  const float* self_in_w  = (const float*)d_in[4];
  const float* self_in_b  = (const float*)d_in[5];
  const float* self_out_w = (const float*)d_in[6];
  const float* self_out_b = (const float*)d_in[7];
  const float* cross_in_w = (const float*)d_in[8];
  const float* cross_in_b = (const float*)d_in[9];
  const float* cross_out_w= (const float*)d_in[10];
  const float* cross_out_b= (const float*)d_in[11];
  const float* ff1_w      = (const float*)d_in[12];
  const float* ff1_b      = (const float*)d_in[13];
  const float* ff2_w      = (const float*)d_in[14];
  const float* ff2_b      = (const float*)d_in[15];
  const float* ln1_g      = (const float*)d_in[16];
  const float* ln1_b      = (const float*)d_in[17];
  const float* ln2_g      = (const float*)d_in[18];
  const float* ln2_b      = (const float*)d_in[19];
  const float* ln3_g      = (const float*)d_in[20];
  const float* ln3_b      = (const float*)d_in[21];
  const float* dense_w    = (const float*)d_in[22];
  const float* dense_b    = (const float*)d_in[23];
  const float* context    = (const float*)d_in[24];
  const int*   source_mask= (const int*)d_in[25];

  float* wsf = (float*)d_ws;
  size_t off = 0;
  auto alloc = [&](size_t n) { float* p = wsf + off; off += (n + 3) & ~(size_t)3; return p; };

  float* XA    = alloc(RR * 768);
  float* XB    = alloc(RR * 768);
  float* XC    = alloc(RR * 768);
  float* qb    = alloc(RR * 768);
  float* attnb = alloc(RR * 768);
  float* tmp   = alloc(RR * 768);
  float* hbuf  = alloc(RR * 768);
  float* ffb   = alloc(RR * 3072);
  float* candV = alloc(RR * LB * 5);
  float* mrow  = alloc(RR * LB);
  float* srow  = alloc(RR * LB);
  float* scores= alloc(32);
  float* ck    = alloc((size_t)NLY * 4 * 128 * 768);
  float* cv    = alloc((size_t)NLY * 4 * 128 * 768);
  const size_t cacheSeg = (size_t)RR * BUFL * 768;   // per (pp, layer)
  float* kcB   = alloc(4 * cacheSeg);                 // [pp][l]
  float* vcB   = alloc(4 * cacheSeg);
  int* candI   = (int*)alloc(RR * LB * 5);
  int* bufs0   = (int*)alloc(RR * BUFL + 12);
  int* bufs1   = (int*)alloc(RR * BUFL + 12);
  int* prevKp  = (int*)alloc(32);
  int* tokp    = (int*)alloc(32);
  const size_t baseFloats = off;

  // transposed weights
  const size_t nSiT = (size_t)768 * 2304, nSoT = (size_t)768 * 768;
  const size_t nCiT = nSiT, nCoT = nSoT, nF1T = (size_t)768 * 3072, nF2T = (size_t)3072 * 768;
  const size_t wtFloats = 2 * (nSiT + nSoT + nCiT + nCoT + nF1T + nF2T) + nSoT;
  const size_t embTFloats = (size_t)768 * kVP;
  const bool useWT = ws_size >= (baseFloats + wtFloats) * 4;
  const bool useET = useWT && ws_size >= (baseFloats + wtFloats + embTFloats) * 4;

  float* siT[2]; float* soT[2]; float* ciT[2]; float* coT[2]; float* f1T[2]; float* f2T[2];
  float* dT = nullptr; float* embT = nullptr;
  if (useWT) {
    for (int l = 0; l < 2; ++l) siT[l] = alloc(nSiT);
    for (int l = 0; l < 2; ++l) soT[l] = alloc(nSoT);
    for (int l = 0; l < 2; ++l) ciT[l] = alloc(nCiT);
    for (int l = 0; l < 2; ++l) coT[l] = alloc(nCoT);
    for (int l = 0; l < 2; ++l) f1T[l] = alloc(nF1T);
    for (int l = 0; l < 2; ++l) f2T[l] = alloc(nF2T);
    dT = alloc(nSoT);
    if (useET) embT = alloc(embTFloats);
  }

  init_k<<<1, 512, 0, stream>>>(bufs0, scores);

  if (useWT) {
    auto T = [&](const float* src, float* dst, int R, int C, int ds) {
      dim3 g((C + 31) / 32, (R + 31) / 32);
      transpose_k<<<g, 256, 0, stream>>>(src, dst, R, C, ds);
    };
    for (int l = 0; l < 2; ++l) {
      T(self_in_w  + (size_t)l * 2304 * 768, siT[l], 2304, 768, 2304);
      T(self_out_w + (size_t)l * 768 * 768,  soT[l], 768, 768, 768);
      T(cross_in_w + (size_t)l * 2304 * 768, ciT[l], 2304, 768, 2304);
      T(cross_out_w+ (size_t)l * 768 * 768,  coT[l], 768, 768, 768);
      T(ff1_w      + (size_t)l * 3072 * 768, f1T[l], 3072, 768, 3072);
      T(ff2_w      + (size_t)l * 768 * 3072, f2T[l], 768, 3072, 768);
    }
    T(dense_w, dT, 768, 768, 768);
    if (useET) T(emb, embT, kV, 768, kVP);
  }

  // cross K/V (once)
  {
    dim3 g(24, 32, 2);
    if (useWT) crosskv_k<true><<<g, 256, 0, stream>>>(context, ciT[0], cross_in_b, ck, cv);
    else       crosskv_k<false><<<g, 256, 0, stream>>>(context, cross_in_w, cross_in_b, ck, cv);
  }
  // NOTE: crosskv_k<true> indexes Wm0 + l*2304*768 which matches ciT[0]/ciT[1] contiguity.

  const int* bc = bufs0;   // captured by ref in lambda
  auto G = [&](const float* Wt, const float* Wg, int wstride,
               const float* bias, int N, int pre, const float* xsrc, const float* tmpin,
               const float* g2, const float* b2, float* xout, int outmode, float* out0,
               float* kcl, float* vcl, int tt,
               int reorder_t, const float* kco, const float* vco, float* kcn2, float* vcn2) {
    dim3 grid(N / 64);
    if (useWT)
      gemm20_k<true><<<grid, 256, 0, stream>>>(Wt, wstride, bias, N, pre, xsrc, tmpin, g2, b2,
        xout, outmode, out0, kcl, vcl, tt, emb, pos, bc, reorder_t, kco, vco, kcn2, vcn2, prevKp);
    else
      gemm20_k<false><<<grid, 256, 0, stream>>>(Wg, wstride, bias, N, pre, xsrc, tmpin, g2, b2,
        xout, outmode, out0, kcl, vcl, tt, emb, pos, bc, reorder_t, kco, vco, kcn2, vcn2, prevKp);
  };

  for (int t = 0; t < TMAX; ++t) {
    bc = (t & 1) ? bufs1 : bufs0;
    int* bn = (t & 1) ? bufs0 : bufs1;
    const int np = (t + 1) & 1, op = t & 1;

    for (int l = 0; l < 2; ++l) {
      float* kNew = kcB + (np * 2 + l) * cacheSeg;
      float* vNew = vcB + (np * 2 + l) * cacheSeg;
      float* kOld = kcB + (op * 2 + l) * cacheSeg;
      float* vOld = vcB + (op * 2 + l) * cacheSeg;
      // qkv (+embed/ln_emb for l0, +ln3(l0) for l1, +cache reorder)
      if (l == 0)
        G(siT[0], self_in_w, 2304, self_in_b, 2304,
          /*pre*/1, nullptr, nullptr, ln_emb_g, ln_emb_b, XA,
          /*outmode*/3, qb, kNew, vNew, t, t, kOld, vOld, kNew, vNew);
      else
        G(siT[1], self_in_w + (size_t)2304 * 768, 2304, self_in_b + 2304, 2304,
          /*pre*/2, XC, tmp, ln3_g, ln3_b, XA,
          /*outmode*/3, qb, kNew, vNew, t, t, kOld, vOld, kNew, vNew);
      self_attn_k<<<dim3(RR, 12), 64, 0, stream>>>(qb, kNew, vNew, attnb, t);
      // self out-proj -> tmp
      G(soT[l], self_out_w + (size_t)l * 768 * 768, 768, self_out_b + l * 768, 768,
        0, attnb, nullptr, nullptr, nullptr, nullptr, 0, tmp,
        nullptr, nullptr, t, 0, nullptr, nullptr, nullptr, nullptr);
      // cross q (+ln1) -> qb ; writes XB
      G(ciT[l], cross_in_w + (size_t)l * 2304 * 768, 2304, cross_in_b + l * 2304, 768,
        2, XA, tmp, ln1_g + l * 768, ln1_b + l * 768, XB, 0, qb,
        nullptr, nullptr, t, 0, nullptr, nullptr, nullptr, nullptr);
      cross_attn_k<<<dim3(RR, 12), 64, 0, stream>>>(
          qb, ck + (size_t)l * 4 * 128 * 768, cv + (size_t)l * 4 * 128 * 768, source_mask, attnb);
      // cross out-proj -> tmp
      G(coT[l], cross_out_w + (size_t)l * 768 * 768, 768, cross_out_b + l * 768, 768,
        0, attnb, nullptr, nullptr, nullptr, nullptr, 0, tmp,
        nullptr, nullptr, t, 0, nullptr, nullptr, nullptr, nullptr);
      // ff1 (+ln2) -> ffb ; writes XC
      G(f1T[l], ff1_w + (size_t)l * 3072 * 768, 3072, ff1_b + l * 3072, 3072,
        2, XB, tmp, ln2_g + l * 768, ln2_b + l * 768, XC, 1, ffb,
        nullptr, nullptr, t, 0, nullptr, nullptr, nullptr, nullptr);
      // ff2 -> tmp
      if (useWT) ff2_k<true><<<48, 1024, 0, stream>>>(f2T[l], ff2_b + l * 768, ffb, tmp);
      else       ff2_k<false><<<48, 1024, 0, stream>>>(ff2_w + (size_t)l * 768 * 3072, ff2_b + l * 768, ffb, tmp);
    }
    // dense head (+ln3 of layer 1, tanh) -> hbuf
    G(dT, dense_w, 768, dense_b, 768,
      2, XC, tmp, ln3_g + 768, ln3_b + 768, nullptr, 2, hbuf,
      nullptr, nullptr, t, 0, nullptr, nullptr, nullptr, nullptr);
    // logits partials
    if (useET) logits_k<true><<<LB, 256, 0, stream>>>(hbuf, embT, candV, candI, mrow, srow);
    else       logits_k<false><<<LB, 256, 0, stream>>>(hbuf, emb, candV, candI, mrow, srow);
    // top-k + buf reorder
    topk_k<<<BB, 256, 0, stream>>>(candV, candI, mrow, srow, scores, bc, bn, t, prevKp, tokp);
  }

  finalize_k<<<1, 64, 0, stream>>>(scores, bufs0, (float*)d_out);
}